// Round 4
// baseline (485.722 us; speedup 1.0000x reference)
//
#include <hip/hip_runtime.h>
#include <hip/hip_cooperative_groups.h>
#include <math.h>

namespace cg = cooperative_groups;

#define BB 8
#define CC 64
#define HH 256
#define WW 256
#define HWp (HH * WW)      /* 65536 */
#define BHW (BB * HWp)     /* 524288 */
#define NK 9

typedef float f32x4 __attribute__((ext_vector_type(4)));

__device__ __forceinline__ float2 bisample(const float2* __restrict__ f, int iy, int ix) {
    bool v = ((unsigned)iy < (unsigned)HH) && ((unsigned)ix < (unsigned)WW);
    int cy = iy < 0 ? 0 : (iy > HH - 1 ? HH - 1 : iy);
    int cx = ix < 0 ? 0 : (ix > WW - 1 ? WW - 1 : ix);
    float2 r = f[cy * WW + cx];
    return v ? r : make_float2(0.f, 0.f);
}

// One cooperative kernel, 4 phases separated by grid.sync().
// Phase1: channel mean+max -> feat (interleaved avg,max per pixel)
// Phase2: deformable 3x3 conv -> outmap, + global sum/sumsq atomics
// Phase3: sigmoid of normalized outmap -> sigmap
// Phase4: out = x * sigmap (NT stores; x should be L3-resident from Phase1)
__global__ __launch_bounds__(256, 4) void fused_kernel(
    const float* __restrict__ x, const float* __restrict__ off,
    const float* __restrict__ wgt, const float* __restrict__ gamma,
    const float* __restrict__ beta, float* __restrict__ feat,
    float* __restrict__ outmap, float* __restrict__ accum,
    float* __restrict__ out) {
    cg::grid_group grid = cg::this_grid();
    const int gsize = gridDim.x * 256;
    const int tid = blockIdx.x * 256 + threadIdx.x;

    if (tid < 2) accum[tid] = 0.f;   // visible to Phase2 after first sync

    // ---------------- Phase 1: reduce over C (float4 per task) -------------
    for (int t = tid; t < BHW / 4; t += gsize) {
        int b = t >> 14;                 // / (HWp/4)
        int p = t & (HWp / 4 - 1);
        const f32x4* xp = reinterpret_cast<const f32x4*>(x) + (size_t)b * CC * (HWp / 4) + p;
        f32x4 s = {0.f, 0.f, 0.f, 0.f};
        f32x4 m = {-INFINITY, -INFINITY, -INFINITY, -INFINITY};
#pragma unroll 16
        for (int c = 0; c < CC; ++c) {
            f32x4 v = xp[(size_t)c * (HWp / 4)];
            s += v;
            m.x = fmaxf(m.x, v.x); m.y = fmaxf(m.y, v.y);
            m.z = fmaxf(m.z, v.z); m.w = fmaxf(m.w, v.w);
        }
        const float inv = 1.0f / CC;
        f32x4 o0 = {s.x * inv, m.x, s.y * inv, m.y};
        f32x4 o1 = {s.z * inv, m.z, s.w * inv, m.w};
        f32x4* fp = reinterpret_cast<f32x4*>(feat) + 2 * (size_t)t;
        fp[0] = o0;
        fp[1] = o1;
    }
    grid.sync();

    // ---------------- Phase 2: deformable conv + stats ---------------------
    {
        float wk[2 * NK];
#pragma unroll
        for (int i = 0; i < 2 * NK; ++i) wk[i] = wgt[i];
        float s1r = 0.f, s2r = 0.f;
        for (int t = tid; t < BHW; t += gsize) {
            int b = t >> 16;
            int p = t & (HWp - 1);
            int h = p >> 8;
            int w = p & (WW - 1);
            const float* ob = off + (size_t)b * (2 * NK) * HWp + p;
            const float2* f = reinterpret_cast<const float2*>(feat) + (size_t)b * HWp;
            float acc = 0.f;
#pragma unroll
            for (int k = 0; k < NK; ++k) {
                float dy = ob[(size_t)(2 * k) * HWp];
                float dx = ob[(size_t)(2 * k + 1) * HWp];
                float py = dy + (float)(h - 1 + k / 3);
                float px = dx + (float)(w - 1 + k % 3);
                float y0 = floorf(py), x0 = floorf(px);
                float wy = py - y0, wx = px - x0;
                int iy0 = (int)y0, ix0 = (int)x0;
                float w00 = (1.f - wy) * (1.f - wx);
                float w01 = (1.f - wy) * wx;
                float w10 = wy * (1.f - wx);
                float w11 = wy * wx;
                float2 c00 = bisample(f, iy0, ix0);
                float2 c01 = bisample(f, iy0, ix0 + 1);
                float2 c10 = bisample(f, iy0 + 1, ix0);
                float2 c11 = bisample(f, iy0 + 1, ix0 + 1);
                float s0 = w00 * c00.x + w01 * c01.x + w10 * c10.x + w11 * c11.x;
                float s1 = w00 * c00.y + w01 * c01.y + w10 * c10.y + w11 * c11.y;
                acc += wk[k] * s0 + wk[NK + k] * s1;
            }
            outmap[t] = acc;
            s1r += acc;
            s2r += acc * acc;
        }
        // block reduce, one atomic pair per block
#pragma unroll
        for (int o = 32; o > 0; o >>= 1) {
            s1r += __shfl_down(s1r, o, 64);
            s2r += __shfl_down(s2r, o, 64);
        }
        __shared__ float ls1[4], ls2[4];
        int lane = threadIdx.x & 63, wid = threadIdx.x >> 6;
        if (lane == 0) { ls1[wid] = s1r; ls2[wid] = s2r; }
        __syncthreads();
        if (threadIdx.x == 0) {
            atomicAdd(&accum[0], ls1[0] + ls1[1] + ls1[2] + ls1[3]);
            atomicAdd(&accum[1], ls2[0] + ls2[1] + ls2[2] + ls2[3]);
        }
    }
    grid.sync();

    // ---------------- Phase 3: sigmoid of normalized outmap -> sigmap ------
    // sigmap aliases feat (feat dead after Phase2).
    {
        float mu = accum[0] * (1.0f / BHW);
        float var = accum[1] * (1.0f / BHW) - mu * mu;
        float rs = rsqrtf(var + 1e-5f);
        float g = gamma[0], be = beta[0];
        for (int t = tid; t < BHW / 4; t += gsize) {
            f32x4 o = reinterpret_cast<const f32x4*>(outmap)[t];
            f32x4 r;
            r.x = 1.f / (1.f + expf(-(g * (o.x - mu) * rs + be)));
            r.y = 1.f / (1.f + expf(-(g * (o.y - mu) * rs + be)));
            r.z = 1.f / (1.f + expf(-(g * (o.z - mu) * rs + be)));
            r.w = 1.f / (1.f + expf(-(g * (o.w - mu) * rs + be)));
            reinterpret_cast<f32x4*>(feat)[t] = r;   // sigmap
        }
    }
    grid.sync();

    // ---------------- Phase 4: out = x * sigmap ----------------------------
    {
        const float* __restrict__ sigmap = feat;
        const int total = BB * CC * (HWp / 4);       // 8388608
        for (int t = tid; t < total; t += gsize) {
            int b = t >> 20;                         // / (CC*HWp/4)
            int rem = t & ((CC * (HWp / 4)) - 1);
            int p4 = rem & (HWp / 4 - 1);
            f32x4 xv = reinterpret_cast<const f32x4*>(x)[(size_t)t];
            f32x4 sv = reinterpret_cast<const f32x4*>(sigmap)[b * (HWp / 4) + p4];
            f32x4 r = xv * sv;
            __builtin_nontemporal_store(r, reinterpret_cast<f32x4*>(out) + t);
        }
    }
}

// ---------------------------------------------------------------------------
extern "C" void kernel_launch(void* const* d_in, const int* in_sizes, int n_in,
                              void* d_out, int out_size, void* d_ws, size_t ws_size,
                              hipStream_t stream) {
    const float* x      = (const float*)d_in[0];
    const float* offset = (const float*)d_in[1];
    const float* weight = (const float*)d_in[2];
    const float* gamma  = (const float*)d_in[3];
    const float* beta   = (const float*)d_in[4];
    float* out = (float*)d_out;

    float* ws     = (float*)d_ws;
    float* feat   = ws;              // 2*BHW floats (interleaved avg,max; reused as sigmap)
    float* outmap = ws + 2 * BHW;    // BHW floats
    float* accum  = ws + 3 * BHW;    // 2 floats

    int occ = 0;
    hipOccupancyMaxActiveBlocksPerMultiprocessor(&occ, fused_kernel, 256, 0);
    if (occ < 1) occ = 1;
    int nblk = occ * 256;            // 256 CUs on MI355X
    if (nblk > 1024) nblk = 1024;

    void* args[] = {(void*)&x, (void*)&offset, (void*)&weight, (void*)&gamma,
                    (void*)&beta, (void*)&feat, (void*)&outmap, (void*)&accum,
                    (void*)&out};
    hipLaunchCooperativeKernel((const void*)fused_kernel, dim3(nblk), dim3(256),
                               args, 0, stream);
}